// Round 12
// baseline (265.150 us; speedup 1.0000x reference)
//
#include <hip/hip_runtime.h>
#include <cstdint>
#include <cstddef>

typedef __bf16 bf16;
typedef __bf16 bf16x2 __attribute__((ext_vector_type(2)));
typedef __bf16 bf16x4 __attribute__((ext_vector_type(4)));
typedef __bf16 bf16x8 __attribute__((ext_vector_type(8)));
typedef float f32x4 __attribute__((ext_vector_type(4)));

#define S_LEN 2048
#define BATCH 2
#define DM 1024
#define NH 16
#define DKH 64
#define MTOT (S_LEN * BATCH)  // 4096

// async global->LDS, 16B per lane; LDS dest = wave-uniform base + lane*16
__device__ __forceinline__ void gload_lds16(const void* g, void* l) {
    __builtin_amdgcn_global_load_lds((const __attribute__((address_space(1))) uint32_t*)g,
                                     (__attribute__((address_space(3))) uint32_t*)l, 16, 0, 0);
}

__device__ __forceinline__ uint32_t pack2(float a, float b) {
    bf16x2 v; v[0] = (bf16)a; v[1] = (bf16)b;
    return __builtin_bit_cast(uint32_t, v);
}

__device__ __forceinline__ void bar() { asm volatile("s_barrier" ::: "memory"); }
__device__ __forceinline__ void lgkm0() { asm volatile("s_waitcnt lgkmcnt(0)" ::: "memory"); }
template<int N>
__device__ __forceinline__ void waitvm() {
    asm volatile("s_waitcnt vmcnt(%0)" :: "n"(N) : "memory");
}

// ---------------- fused fp32 -> bf16 convert ----------------
struct ConvArgs { const float* src[7]; bf16* dst[7]; };

__global__ __launch_bounds__(256) void convert_all(ConvArgs a) {
    int gid = blockIdx.x * 256 + threadIdx.x;
    int tid, off;
    if (gid < 3 * 524288) { tid = gid >> 19; off = gid & 524287; }
    else { int r = gid - 3 * 524288; tid = 3 + (r >> 17); off = r & 131071; }
    const float4* s4 = (const float4*)a.src[tid];
    float4 x = s4[2 * off], y = s4[2 * off + 1];
    bf16x8 v;
    v[0] = (bf16)x.x; v[1] = (bf16)x.y; v[2] = (bf16)x.z; v[3] = (bf16)x.w;
    v[4] = (bf16)y.x; v[5] = (bf16)y.y; v[6] = (bf16)y.z; v[7] = (bf16)y.w;
    *(bf16x8*)(a.dst[tid] + 8 * (size_t)off) = v;
}

// ---------------- 256x256 8-phase GEMM for QKV (R12) ----------------
// R12 = R11 with the LDS slot race FIXED. R11 bug: A-slot h is a 128-row half
// read by its wave-group in ph1 (local rows 0..63) AND ph3 (64..127); staging
// stA(tt+2,0) in ph2 wrote parity (tt+2)&1 == tt&1 (CURRENT) while ph3 reads
// were pending -> absmax 0.23. Fix: A slots re-staged only in ph4 body (after
// ph3 closing bar); B slots (read ph1+ph2) re-staged in ph3 body. Explicit
// lgkmcnt(0) pinned between phase bars (volatile asm keeps mutual order) so
// every wave's ds_reads complete before it passes the closing bar -> the
// one-barrier-later async overwrites are safe regardless of MFMA sinking
// (rule #18). Issue order/iter: B1(t+1)@ph1, B0(t+2)@ph3, A0+A1(t+2)@ph4 =
// 8 loads; waitvm<6> at ph4 certifies exactly tile t+1 (14 outstanding -> 8
// oldest = B0,A0,A1,B1 of t+1). Swizzle math identical to R9 (verified).
struct QKVArgs {
    const bf16* A[3]; const bf16* W[3]; const float* bias[3];
    void* out[3]; const float* cs[3]; const float* sn[3]; int mode[3];
};

template<int TMH, int TNH>
__device__ __forceinline__ void qmfma(f32x4 (&acc)[8][4], const bf16x8 (&Af)[4][2],
                                      const bf16x8 (&Bf)[2][2], int mode) {
#pragma unroll
    for (int i = 0; i < 4; ++i)
#pragma unroll
        for (int j = 0; j < 2; ++j)
#pragma unroll
            for (int h2 = 0; h2 < 2; ++h2) {
                if (mode == 1)
                    acc[TMH * 4 + i][TNH * 2 + j] = __builtin_amdgcn_mfma_f32_16x16x32_bf16(
                        Bf[j][h2], Af[i][h2], acc[TMH * 4 + i][TNH * 2 + j], 0, 0, 0);
                else
                    acc[TMH * 4 + i][TNH * 2 + j] = __builtin_amdgcn_mfma_f32_16x16x32_bf16(
                        Af[i][h2], Bf[j][h2], acc[TMH * 4 + i][TNH * 2 + j], 0, 0, 0);
            }
}

__global__ __launch_bounds__(512, 2) void gemm_qkv(QKVArgs args) {
    __shared__ __align__(16) bf16 As[2 * 16384];  // parity x (2 half x [128][64])
    __shared__ __align__(16) bf16 Bs[2 * 16384];
    int z = blockIdx.z;
    const bf16* __restrict__ A  = args.A[z];
    const bf16* __restrict__ Bt = args.W[z];
    const float* __restrict__ bias = args.bias[z];
    void* out = args.out[z];
    int mode = args.mode[z];
    const float* cosp = args.cs[z];
    const float* sinp = args.sn[z];

    int bid = blockIdx.y * 4 + blockIdx.x;       // 0..63 per z (nwg%8==0)
    int swz = (bid & 7) * 8 + (bid >> 3);        // bijective 8x8 digit swap
    int bx = swz & 3, by = swz >> 2;
    int m0 = by * 256, n0 = bx * 256;

    int t = threadIdx.x;
    int lane = t & 63, wid = t >> 6;
    int lm = lane & 15, quad = lane >> 4;
    int wm = (wid >> 2) * 128, wn = (wid & 3) * 64;
    const int ahalf = wid >> 2;              // A LDS half this wave reads
    const int bhalf = (wid & 3) >> 1;        // B LDS half
    const int brow0 = wn & 64;               // local row base within B half
    const int rsw = lm & 7;                  // read-side swizzle key

    f32x4 acc[8][4] = {};

    // staging: thread covers row wid*8+(lane>>3) (+h*128, +64), col16 swizzled
    int csw = ((lane & 7) ^ ((lane >> 3) & 7)) * 8;
    const bf16* Ag = A + (size_t)(m0 + wid * 8 + (lane >> 3)) * DM + csw;
    const bf16* Bg = Bt + (size_t)(n0 + wid * 8 + (lane >> 3)) * DM + csw;

    auto stA = [&](int tile, int h) {
        bf16* d = As + (tile & 1) * 16384 + h * 8192 + wid * 512;
        const bf16* s = Ag + (size_t)(h * 128) * DM + tile * 64;
        gload_lds16(s, d);
        gload_lds16(s + (size_t)64 * DM, d + 4096);
    };
    auto stB = [&](int tile, int h) {
        bf16* d = Bs + (tile & 1) * 16384 + h * 8192 + wid * 512;
        const bf16* s = Bg + (size_t)(h * 128) * DM + tile * 64;
        gload_lds16(s, d);
        gload_lds16(s + (size_t)64 * DM, d + 4096);
    };

    // prologue: tile0 complete (8 loads), then tile1 {B0,A0,A1} (6 loads);
    // waitvm<6> certifies exactly tile0; leftover = [B0,A0,A1](1)
    stA(0, 0); stA(0, 1); stB(0, 0); stB(0, 1);
    stB(1, 0); stA(1, 0); stA(1, 1);
    waitvm<6>();
    bar();

    bf16x8 af[4][2], b0[2][2], b1[2][2];

    for (int tt = 0; tt < 16; ++tt) {
        const bf16* Ab = As + (tt & 1) * 16384 + ahalf * 8192;
        const bf16* Bb = Bs + (tt & 1) * 16384 + bhalf * 8192;
        // ---- ph1: read A-lo + b0; stage B-h1(t+1) [parity^1: last read ph2 of tt-1]
#pragma unroll
        for (int i = 0; i < 4; ++i) {
            int r = i * 16 + lm;                         // local rows 0..63
#pragma unroll
            for (int h2 = 0; h2 < 2; ++h2)
                af[i][h2] = *(const bf16x8*)(Ab + r * 64 + (((h2 * 4 + quad) ^ rsw) * 8));
        }
#pragma unroll
        for (int j = 0; j < 2; ++j) {
            int r = brow0 + j * 16 + lm;                 // b0: local rows +0..31
#pragma unroll
            for (int h2 = 0; h2 < 2; ++h2)
                b0[j][h2] = *(const bf16x8*)(Bb + r * 64 + (((h2 * 4 + quad) ^ rsw) * 8));
        }
        if (tt + 1 < 16) stB(tt + 1, 1);
        bar();
        lgkm0();   // pinned between bars: reads drained before closing bar
        __builtin_amdgcn_s_setprio(1);
        qmfma<0, 0>(acc, af, b0, mode);
        __builtin_amdgcn_s_setprio(0);
        bar();
        // ---- ph2: read b1
#pragma unroll
        for (int j = 0; j < 2; ++j) {
            int r = brow0 + 32 + j * 16 + lm;            // b1: local rows +32..63
#pragma unroll
            for (int h2 = 0; h2 < 2; ++h2)
                b1[j][h2] = *(const bf16x8*)(Bb + r * 64 + (((h2 * 4 + quad) ^ rsw) * 8));
        }
        bar();
        lgkm0();
        __builtin_amdgcn_s_setprio(1);
        qmfma<0, 1>(acc, af, b1, mode);
        __builtin_amdgcn_s_setprio(0);
        bar();
        // ---- ph3: read A-hi; stage B-h0(t+2) [B slots free after ph2 closing bar]
#pragma unroll
        for (int i = 0; i < 4; ++i) {
            int r = 64 + i * 16 + lm;                    // local rows 64..127
#pragma unroll
            for (int h2 = 0; h2 < 2; ++h2)
                af[i][h2] = *(const bf16x8*)(Ab + r * 64 + (((h2 * 4 + quad) ^ rsw) * 8));
        }
        if (tt + 2 < 16) stB(tt + 2, 0);
        bar();
        lgkm0();
        __builtin_amdgcn_s_setprio(1);
        qmfma<1, 0>(acc, af, b0, mode);
        __builtin_amdgcn_s_setprio(0);
        bar();
        // ---- ph4: stage A-h0,A-h1(t+2) [A slots free after ph3 closing bar]
        if (tt + 2 < 16) { stA(tt + 2, 0); stA(tt + 2, 1); }
        bar();
        __builtin_amdgcn_s_setprio(1);
        qmfma<1, 1>(acc, af, b1, mode);
        __builtin_amdgcn_s_setprio(0);
        if (tt + 2 < 16)      waitvm<6>();   // certify tile t+1; 3 halves in flight
        else if (tt + 1 < 16) waitvm<0>();   // tail: certify final tile
        bar();                               // publish tile t+1
    }

    if (mode == 1) {
        // acc[i][j]: row(quad*4+r) = d local to j-tile, col(lm) = token local to i-tile
#pragma unroll
        for (int j = 0; j < 4; ++j) {
#pragma unroll
            for (int r = 0; r < 4; ++r) {
                int d = n0 + wn + j * 16 + quad * 4 + r;
                float bv = bias[d];
                int h = d >> 6, dk = d & 63;
#pragma unroll
                for (int i = 0; i < 8; ++i) {
                    int token = m0 + wm + i * 16 + lm;
                    int s = token >> 1, b = token & 1;
                    ((bf16*)out)[((size_t)(b * NH + h) * DKH + dk) * S_LEN + s] =
                        (bf16)(acc[i][j][r] + bv);
                }
            }
        }
        return;
    }
    // bias first (rope needs biased partner values)
#pragma unroll
    for (int j = 0; j < 4; ++j) {
        float bcol = bias[n0 + wn + j * 16 + lm];
#pragma unroll
        for (int i = 0; i < 8; ++i)
#pragma unroll
            for (int r = 0; r < 4; ++r) acc[i][j][r] += bcol;
    }
#pragma unroll
    for (int i = 0; i < 8; ++i) {
#pragma unroll
        for (int j = 0; j < 4; ++j) {
            int col = n0 + wn + j * 16 + lm;
#pragma unroll
            for (int r = 0; r < 4; ++r) {
                int row = m0 + wm + i * 16 + quad * 4 + r;
                float val = acc[i][j][r];
                // mode 3/4: rope; partner dk^32 = acc[i][j^2][r] (same lane/wave)
                int s = row >> 1, dk = col & 63;
                float c = cosp[s * 64 + dk], sn = sinp[s * 64 + dk];
                float partner = acc[i][j ^ 2][r];
                float v2 = val * c + (dk < 32 ? -partner : partner) * sn;
                if (mode == 3) v2 *= 0.125f * 1.44269504088896f;  // 1/sqrt(DK)*log2(e)
                ((bf16*)out)[(size_t)row * DM + col] = (bf16)v2;
            }
        }
    }
}

// ---------------- R9 128x64 2-phase core (kept for gemm_one only) ----------------
template<int MI>
__device__ __forceinline__ void gemm_core(const bf16* __restrict__ A, const bf16* __restrict__ Bt,
                                          const float* __restrict__ bias, void* __restrict__ out,
                                          int mode, const float* __restrict__ cosp,
                                          const float* __restrict__ sinp, bf16* As, bf16* Bs,
                                          int bx, int by) {
    constexpr int TN = (MI == 4) ? 128 : 64;
    constexpr int ASZ = 8192;
    constexpr int BSZ = (TN == 128) ? 8192 : 4096;
    constexpr int SL  = (MI == 4) ? 8 : 6;
    constexpr int NSTEP = DM / 64;
    int t = threadIdx.x;
    int lane = t & 63, wave = t >> 6;
    int lm = lane & 15, quad = lane >> 4;
    int m0 = by * 128, n0 = bx * TN;
    int wm, wn;
    if constexpr (MI == 4) { wm = (wave >> 1) * 64; wn = (wave & 1) * 64; }
    else { wm = wave * 32; wn = 0; }
    f32x4 acc[MI][4] = {};

    int rw = lane >> 3;
    int csw = ((lane & 7) ^ rw) * 8;
    const bf16* agp = A + (size_t)(m0 + wave * 32 + rw) * DM + csw;
    const bf16* bgp;
    if constexpr (MI == 4) bgp = Bt + (size_t)(n0 + wave * 32 + rw) * DM + csw;
    else                   bgp = Bt + (size_t)(n0 + wave * 16 + rw) * DM + csw;

    auto stage = [&](int k0, bf16* Ab, bf16* Bb) {
#pragma unroll
        for (int q = 0; q < 4; ++q)
            gload_lds16(agp + (size_t)q * 8 * DM + k0, Ab + wave * 2048 + q * 512);
        if constexpr (MI == 4) {
#pragma unroll
            for (int q = 0; q < 4; ++q)
                gload_lds16(bgp + (size_t)q * 8 * DM + k0, Bb + wave * 2048 + q * 512);
        } else {
#pragma unroll
            for (int q = 0; q < 2; ++q)
                gload_lds16(bgp + (size_t)q * 8 * DM + k0, Bb + wave * 1024 + q * 512);
        }
    };
    const int rsw = lm & 7;
    auto compute = [&](const bf16* Ar, const bf16* Br) {
        __builtin_amdgcn_s_setprio(1);
#pragma unroll
        for (int h = 0; h < 2; ++h) {
            const int slot = ((h * 4 + quad) ^ rsw) * 8;
            bf16x8 af[MI], bfr[4];
#pragma unroll
            for (int i = 0; i < MI; ++i)
                af[i] = *(const bf16x8*)(Ar + (wm + i * 16 + lm) * 64 + slot);
#pragma unroll
            for (int j = 0; j < 4; ++j)
                bfr[j] = *(const bf16x8*)(Br + (wn + j * 16 + lm) * 64 + slot);
            if (mode == 1) {
#pragma unroll
                for (int i = 0; i < MI; ++i)
#pragma unroll
                    for (int j = 0; j < 4; ++j)
                        acc[i][j] = __builtin_amdgcn_mfma_f32_16x16x32_bf16(bfr[j], af[i], acc[i][j], 0, 0, 0);
            } else {
#pragma unroll
                for (int i = 0; i < MI; ++i)
#pragma unroll
                    for (int j = 0; j < 4; ++j)
                        acc[i][j] = __builtin_amdgcn_mfma_f32_16x16x32_bf16(af[i], bfr[j], acc[i][j], 0, 0, 0);
            }
        }
        __builtin_amdgcn_s_setprio(0);
    };

    stage(0, As, Bs);
    stage(64, As + ASZ, Bs + BSZ);
    waitvm<SL>();
    bar();
#pragma unroll
    for (int s = 0; s < NSTEP; ++s) {
        const int cur = s & 1;
        compute(As + cur * ASZ, Bs + cur * BSZ);
        if (s == NSTEP - 1) break;
        bar();
        if (s + 2 < NSTEP) {
            stage((s + 2) * 64, As + cur * ASZ, Bs + cur * BSZ);
            waitvm<SL>();
        } else {
            waitvm<0>();
        }
        bar();
    }
    if (mode == 1) {
#pragma unroll
        for (int j = 0; j < 4; ++j) {
#pragma unroll
            for (int r = 0; r < 4; ++r) {
                int d = n0 + wn + j * 16 + quad * 4 + r;
                float bv = bias[d];
                int h = d >> 6, dk = d & 63;
#pragma unroll
                for (int i = 0; i < MI; ++i) {
                    int token = m0 + wm + i * 16 + lm;
                    int s = token >> 1, b = token & 1;
                    ((bf16*)out)[((size_t)(b * NH + h) * DKH + dk) * S_LEN + s] =
                        (bf16)(acc[i][j][r] + bv);
                }
            }
        }
        return;
    }
#pragma unroll
    for (int j = 0; j < 4; ++j) {
        float bcol = bias[n0 + wn + j * 16 + lm];
#pragma unroll
        for (int i = 0; i < MI; ++i)
#pragma unroll
            for (int r = 0; r < 4; ++r) acc[i][j][r] += bcol;
    }
#pragma unroll
    for (int i = 0; i < MI; ++i) {
#pragma unroll
        for (int j = 0; j < 4; ++j) {
            int col = n0 + wn + j * 16 + lm;
#pragma unroll
            for (int r = 0; r < 4; ++r) {
                int row = m0 + wm + i * 16 + quad * 4 + r;
                float val = acc[i][j][r];
                if (mode == 2) {
                    ((float*)out)[(size_t)row * DM + col] = val;
                } else {
                    int s = row >> 1, dk = col & 63;
                    float c = cosp[s * 64 + dk], sn = sinp[s * 64 + dk];
                    float partner = acc[i][j ^ 2][r];
                    float v2 = val * c + (dk < 32 ? -partner : partner) * sn;
                    if (mode == 3) v2 *= 0.125f * 1.44269504088896f;
                    ((bf16*)out)[(size_t)row * DM + col] = (bf16)v2;
                }
            }
        }
    }
}

__global__ __launch_bounds__(256, 2) void gemm_one(const bf16* __restrict__ A, const bf16* __restrict__ Bt,
                                                   const float* __restrict__ bias, void* __restrict__ out) {
    __shared__ __align__(16) bf16 As[2 * 8192];
    __shared__ __align__(16) bf16 Bs[2 * 4096];
    int bid = blockIdx.y * 16 + blockIdx.x;
    int swz = (bid & 7) * 64 + (bid >> 3);
    int bx = swz & 15, by = swz >> 4;
    gemm_core<2>(A, Bt, bias, out, 2, nullptr, nullptr, As, Bs, bx, by);
}

// ---------------- Flash attention v6 (R8, kept) ----------------
__global__ __launch_bounds__(256, 2) void flash_kernel(const bf16* __restrict__ qp, const bf16* __restrict__ kp,
                                                       const bf16* __restrict__ vT, bf16* __restrict__ ctx) {
    int qta = blockIdx.x;        // 0..15
    int qtb = 31 - qta;          // 16..31
    int bh = blockIdx.y;
    int b = bh >> 4, h = bh & 15;
    int t = threadIdx.x, lane = t & 63, wave = t >> 6;
    int lm = lane & 15, quad = lane >> 4;
    __shared__ __align__(16) bf16 Ks[2][64 * 64];
    __shared__ __align__(16) bf16 Vs[2][64 * 64];
    __shared__ __align__(16) uint32_t Pb[4][16 * 37];
    uint32_t* pw = &Pb[wave][0];
    const int q0[2] = {qta * 64 + wave * 16, qtb * 64 + wave * 16};

    bf16x8 aq[2][2];
#pragma unroll
    for (int u = 0; u < 2; ++u) {
        const bf16* qrow = qp + ((size_t)(q0[u] + lm) * BATCH + b) * DM + h * DKH;
        aq[u][0] = *(const bf16x8*)(qrow + quad * 8);
        aq[u][1] = *(const bf16x8*)(qrow + 32 + quad * 8);
    }
    f32x4 o[2][4] = {};
    float l_acc[2] = {0.f, 0.f};

    int r0 = t >> 3, c0 = t & 7;
    int r1 = r0 + 32;
    const bf16* kg0 = kp + ((size_t)r0 * BATCH + b) * DM + h * DKH + c0 * 8;
    const bf16* kg1 = kp + ((size_t)r1 * BATCH + b) * DM + h * DKH + c0 * 8;
    const bf16* vg0 = vT + ((size_t)(bh * DKH + r0)) * S_LEN + c0 * 8;
    const bf16* vg1 = vT + ((size_t)(bh * DKH + r1)) * S_LEN + c0 * 8;
    int lk0 = r0 * 64 + (c0 ^ (r0 & 7)) * 8;
    int lk1 = r1 * 64 + (c0 ^ (r1 & 7)) * 8;
    const size_t kstep = (size_t)64 * BATCH * DM;

    const int niter = qtb + 1;
    bf16x8 ka = *(const bf16x8*)kg0;
    bf16x8 kb2 = *(const bf16x8*)kg1;
    bf16x8 va = *(const bf16x8*)vg0;
    bf16x8 vb2 = *(const bf16x8*)vg1;
    *(bf16x8*)(Ks[0] + lk0) = ka;
    *(bf16x8*)(Ks[0] + lk1) = kb2;
    *(bf16x8*)(Vs[0] + lk0) = va;
    *(bf16x8*)(Vs[0] + lk1) = vb2;
    __syncthreads();

    for (int it = 0; it < niter; ++it) {
        const int cur = it & 1;
        int kv0 = it << 6;
        bool hn = (it + 1) < niter;
        if (hn) {
            size_t koff = (size_t)(it + 1) * kstep;
            ka  = *(const bf16x8*)(kg0 + koff);
            kb2 = *(const bf16x8*)(kg1 + koff);
            va  = *(const bf16x8*)(vg0 + (it + 1) * 64);
            vb2 = *(const bf16x8*)(vg1 + (it + 1) * 64);
        }
        bf16x8 kf[4][2];
#pragma unroll
        for (int nt = 0; nt < 4; ++nt) {
            int krow = nt * 16 + lm;
            kf[nt][0] = *(const bf16x8*)(Ks[cur] + krow * 64 + ((quad ^ (krow & 7)) * 8));
            kf[nt][1] = *(const bf16x8*)(Ks[cur] + krow * 64 + (((quad + 4) ^ (krow & 7)) * 8));
        }
#pragma unroll
        for (int u = 0; u < 2; ++u) {
            if (u == 0 && kv0 > q0[0] + 15) continue;
            const f32x4 zero = {0.f, 0.f, 0.f, 0.f};
            f32x4 sc[4];
            __builtin_amdgcn_s_setprio(1);
#pragma unroll
            for (int nt = 0; nt < 4; ++nt) {
                sc[nt] = __builtin_amdgcn_mfma_f32_16x16x32_bf16(kf[nt][0], aq[u][0], zero, 0, 0, 0);
                sc[nt] = __builtin_amdgcn_mfma_f32_16x16x32_bf16(kf[nt][1], aq[u][1], sc[nt], 0, 0, 0);
            }
            __builtin_amdgcn_s_setprio(0);
            if (kv0 + 63 > q0[u]) {
#pragma unroll
                for (int nt = 0; nt < 4; ++nt)
#pragma unroll
                    for (int r = 0; r < 4; ++r) {
                        int kvg = kv0 + nt * 16 + quad * 4 + r;
                        if (kvg > q0[u] + lm) sc[nt][r] = -1e30f;
                    }
            }
            float rs = 0.f;
            uint32_t pk[8];
#pragma unroll
            for (int nt = 0; nt < 4; ++nt)
#pragma unroll
                for (int rp = 0; rp < 2; ++rp) {
                    float p0 = exp2f(sc[nt][2 * rp]);
                    float p1 = exp2f(sc[nt][2 * rp + 1]);
                    rs += p0 + p1;
                    pk[nt * 2 + rp] = pack2(p0, p1);
                }
            l_acc[u] += rs;
#pragma unroll
            for (int nt = 0; nt < 4; ++nt)
#pragma unroll
                for (int rp = 0; rp < 2; ++rp)
                    pw[lm * 37 + nt * 8 + quad * 2 + rp] = pk[nt * 2 + rp];
            __builtin_amdgcn_wave_barrier();
            const uint32_t* pr = pw + lm * 37;
            bf16x8 pf0 = *(const bf16x8*)(pr + quad * 4);
            bf16x8 pf1 = *(const bf16x8*)(pr + 16 + quad * 4);
            __builtin_amdgcn_s_setprio(1);
#pragma unroll
            for (int dt = 0; dt < 4; ++dt) {
                int vrow = dt * 16 + lm;
                bf16x8 vf0 = *(const bf16x8*)(Vs[cur] + vrow * 64 + ((quad ^ (vrow & 7)) * 8));
                bf16x8 vf1 = *(const bf16x8*)(Vs[cur] + vrow * 64 + (((quad + 4) ^ (vrow & 7)) * 8));
                o[u][dt] = __builtin_amdgcn_mfma_f32_16x16x32_bf16(vf0, pf0, o[u][dt], 0, 0, 0);
                o[u][dt] = __builtin_amdgcn_mfma_f32_16x16x32_bf16(vf1, pf1, o[u][dt], 0, 0, 0);
            }
            __builtin_amdgcn_s_setprio(0);
            __builtin_amdgcn_wave_barrier();
        }
        if (hn) {
            *(bf16x8*)(Ks[cur ^ 1] + lk0) = ka;
            *(bf16x8*)(Ks[cur ^ 1] + lk1) = kb2;
            *(bf16x8*)(Vs[cur ^ 1] + lk0) = va;
            *(bf16x8*)(Vs[cur ^ 1] + lk1) = vb2;
        }
        __syncthreads();
    }
#pragma unroll
    for (int u = 0; u < 2; ++u) {
        float l = l_acc[u];
        l += __shfl_xor(l, 16, 64);
        l += __shfl_xor(l, 32, 64);
        float linv = 1.f / l;
        int qg = q0[u] + lm;
        bf16* crow = ctx + ((size_t)qg * BATCH + b) * DM + h * DKH;
#pragma unroll
        for (int dt = 0; dt < 4; ++dt) {
            bf16x4 v;
#pragma unroll
            for (int r = 0; r < 4; ++r) v[r] = (bf16)(o[u][dt][r] * linv);
            *(bf16x4*)(crow + dt * 16 + quad * 4) = v;
        }
    }
}

extern "C" void kernel_launch(void* const* d_in, const int* in_sizes, int n_in,
                              void* d_out, int out_size, void* d_ws, size_t ws_size,
                              hipStream_t stream) {
    const float* Q    = (const float*)d_in[0];
    const float* K    = (const float*)d_in[1];
    const float* V    = (const float*)d_in[2];
    const float* Wq   = (const float*)d_in[3];
    const float* bq   = (const float*)d_in[4];
    const float* Wk   = (const float*)d_in[5];
    const float* bk   = (const float*)d_in[6];
    const float* Wv   = (const float*)d_in[7];
    const float* bv   = (const float*)d_in[8];
    const float* Wo   = (const float*)d_in[9];
    const float* bo   = (const float*)d_in[10];
    const float* qcos = (const float*)d_in[11];
    const float* qsin = (const float*)d_in[12];
    const float* kcos = (const float*)d_in[13];
    const float* ksin = (const float*)d_in[14];
    // d_in[15] = mask: deterministic causal triu(k=1); applied analytically.

    char* ws = (char*)d_ws;
    const size_t SZ_ACT = (size_t)MTOT * DM * sizeof(bf16);  // 8 MiB
    const size_t SZ_W   = (size_t)DM * DM * sizeof(bf16);    // 2 MiB
    bf16* qb  = (bf16*)ws; ws += SZ_ACT;
    bf16* kb  = (bf16*)ws; ws += SZ_ACT;
    bf16* vb  = (bf16*)ws; ws += SZ_ACT;
    bf16* wqb = (bf16*)ws; ws += SZ_W;
    bf16* wkb = (bf16*)ws; ws += SZ_W;
    bf16* wvb = (bf16*)ws; ws += SZ_W;
    bf16* wob = (bf16*)ws; ws += SZ_W;
    bf16* qpr = (bf16*)ws; ws += SZ_ACT;
    bf16* kpr = (bf16*)ws; ws += SZ_ACT;
    bf16* vTp = (bf16*)ws; ws += SZ_ACT;
    bf16* ctx = (bf16*)ws; ws += SZ_ACT;

    ConvArgs ca;
    ca.src[0] = Q;  ca.dst[0] = qb;
    ca.src[1] = K;  ca.dst[1] = kb;
    ca.src[2] = V;  ca.dst[2] = vb;
    ca.src[3] = Wq; ca.dst[3] = wqb;
    ca.src[4] = Wk; ca.dst[4] = wkb;
    ca.src[5] = Wv; ca.dst[5] = wvb;
    ca.src[6] = Wo; ca.dst[6] = wob;
    convert_all<<<8192, 256, 0, stream>>>(ca);

    QKVArgs qa;
    qa.A[0] = qb; qa.W[0] = wqb; qa.bias[0] = bq; qa.out[0] = qpr; qa.mode[0] = 3; qa.cs[0] = qcos; qa.sn[0] = qsin;
    qa.A[1] = kb; qa.W[1] = wkb; qa.bias[1] = bk; qa.out[1] = kpr; qa.mode[1] = 4; qa.cs[1] = kcos; qa.sn[1] = ksin;
    qa.A[2] = vb; qa.W[2] = wvb; qa.bias[2] = bv; qa.out[2] = vTp; qa.mode[2] = 1; qa.cs[2] = nullptr; qa.sn[2] = nullptr;
    gemm_qkv<<<dim3(DM / 256, MTOT / 256, 3), 512, 0, stream>>>(qa);

    flash_kernel<<<dim3(16, BATCH * NH), 256, 0, stream>>>(qpr, kpr, vTp, ctx);

    gemm_one<<<dim3(DM / 64, MTOT / 128), 256, 0, stream>>>(ctx, wob, bo, (float*)d_out);
}

// Round 13
// 264.032 us; speedup vs baseline: 1.0042x; 1.0042x over previous
//
#include <hip/hip_runtime.h>
#include <cstdint>
#include <cstddef>

typedef __bf16 bf16;
typedef __bf16 bf16x2 __attribute__((ext_vector_type(2)));
typedef __bf16 bf16x4 __attribute__((ext_vector_type(4)));
typedef __bf16 bf16x8 __attribute__((ext_vector_type(8)));
typedef float f32x4 __attribute__((ext_vector_type(4)));

#define S_LEN 2048
#define BATCH 2
#define DM 1024
#define NH 16
#define DKH 64
#define MTOT (S_LEN * BATCH)  // 4096

// async global->LDS, 16B per lane; LDS dest = wave-uniform base + lane*16
__device__ __forceinline__ void gload_lds16(const void* g, void* l) {
    __builtin_amdgcn_global_load_lds((const __attribute__((address_space(1))) uint32_t*)g,
                                     (__attribute__((address_space(3))) uint32_t*)l, 16, 0, 0);
}

__device__ __forceinline__ uint32_t pack2(float a, float b) {
    bf16x2 v; v[0] = (bf16)a; v[1] = (bf16)b;
    return __builtin_bit_cast(uint32_t, v);
}

// raw barrier + counted vmcnt (T4): __syncthreads would drain vmcnt(0)
__device__ __forceinline__ void bar() { asm volatile("s_barrier" ::: "memory"); }
template<int N>
__device__ __forceinline__ void waitvm() {
    asm volatile("s_waitcnt vmcnt(%0)" :: "n"(N) : "memory");
}

// ---------------- fused fp32 -> bf16 convert ----------------
struct ConvArgs { const float* src[7]; bf16* dst[7]; };

__global__ __launch_bounds__(256) void convert_all(ConvArgs a) {
    int gid = blockIdx.x * 256 + threadIdx.x;
    int tid, off;
    if (gid < 3 * 524288) { tid = gid >> 19; off = gid & 524287; }
    else { int r = gid - 3 * 524288; tid = 3 + (r >> 17); off = r & 131071; }
    const float4* s4 = (const float4*)a.src[tid];
    float4 x = s4[2 * off], y = s4[2 * off + 1];
    bf16x8 v;
    v[0] = (bf16)x.x; v[1] = (bf16)x.y; v[2] = (bf16)x.z; v[3] = (bf16)x.w;
    v[4] = (bf16)y.x; v[5] = (bf16)y.y; v[6] = (bf16)y.z; v[7] = (bf16)y.w;
    *(bf16x8*)(a.dst[tid] + 8 * (size_t)off) = v;
}

// ---------------- GEMM core: C = A(M,K) @ Bt(N,K)^T + bias ----------------
// R13: gemm_qkv REVERTED byte-exact to R9 (best verified: 59-60us, wall 262.0).
// R9 = full-line staging granule (8 rows x 128B lines per gload_lds), row-major
// [128][64] LDS with G4 XOR swizzle (rule-#21 involution, conflicts=0), T4
// depth-2 counted-vmcnt pipeline, T5 setprio, (256,2).
// STRUCTURE LEDGER (do not revisit): R6 BK=32/3-blk co-residency (72us);
// R7 direct-to-reg (141us scratch spill); R12 256^2 8-phase port (65.7us —
// VGPR cap 128 pinched acc[8][4], 192 blocks = 25% CUs idle; catalog's
// m248 geometry doesn't transfer to K=1024 3-GEMM-batched here).
// MI=4: 2x2 waves, N-tile 128 (qkv).  MI=2: 4x1 waves, N-tile 64 (gemm_one).
// mode 1: V^T (B,H,DK,S) bf16 via swapped-operand C^T | mode 2: fp32 row-major
// mode 3: Q + rope + qscale | mode 4: K + rope
template<int MI>
__device__ __forceinline__ void gemm_core(const bf16* __restrict__ A, const bf16* __restrict__ Bt,
                                          const float* __restrict__ bias, void* __restrict__ out,
                                          int mode, const float* __restrict__ cosp,
                                          const float* __restrict__ sinp, bf16* As, bf16* Bs,
                                          int bx, int by) {
    constexpr int TN = (MI == 4) ? 128 : 64;
    constexpr int ASZ = 8192;
    constexpr int BSZ = (TN == 128) ? 8192 : 4096;
    constexpr int SL  = (MI == 4) ? 8 : 6;
    constexpr int NSTEP = DM / 64;
    int t = threadIdx.x;
    int lane = t & 63, wave = t >> 6;
    int lm = lane & 15, quad = lane >> 4;
    int m0 = by * 128, n0 = bx * TN;
    int wm, wn;
    if constexpr (MI == 4) { wm = (wave >> 1) * 64; wn = (wave & 1) * 64; }
    else { wm = wave * 32; wn = 0; }
    f32x4 acc[MI][4] = {};

    int rw = lane >> 3;
    int csw = ((lane & 7) ^ rw) * 8;
    const bf16* agp = A + (size_t)(m0 + wave * 32 + rw) * DM + csw;
    const bf16* bgp;
    if constexpr (MI == 4) bgp = Bt + (size_t)(n0 + wave * 32 + rw) * DM + csw;
    else                   bgp = Bt + (size_t)(n0 + wave * 16 + rw) * DM + csw;

    auto stage = [&](int k0, bf16* Ab, bf16* Bb) {
#pragma unroll
        for (int q = 0; q < 4; ++q)
            gload_lds16(agp + (size_t)q * 8 * DM + k0, Ab + wave * 2048 + q * 512);
        if constexpr (MI == 4) {
#pragma unroll
            for (int q = 0; q < 4; ++q)
                gload_lds16(bgp + (size_t)q * 8 * DM + k0, Bb + wave * 2048 + q * 512);
        } else {
#pragma unroll
            for (int q = 0; q < 2; ++q)
                gload_lds16(bgp + (size_t)q * 8 * DM + k0, Bb + wave * 1024 + q * 512);
        }
    };
    const int rsw = lm & 7;
    auto compute = [&](const bf16* Ar, const bf16* Br) {
        __builtin_amdgcn_s_setprio(1);
#pragma unroll
        for (int h = 0; h < 2; ++h) {
            const int slot = ((h * 4 + quad) ^ rsw) * 8;
            bf16x8 af[MI], bfr[4];
#pragma unroll
            for (int i = 0; i < MI; ++i)
                af[i] = *(const bf16x8*)(Ar + (wm + i * 16 + lm) * 64 + slot);
#pragma unroll
            for (int j = 0; j < 4; ++j)
                bfr[j] = *(const bf16x8*)(Br + (wn + j * 16 + lm) * 64 + slot);
            if (mode == 1) {
#pragma unroll
                for (int i = 0; i < MI; ++i)
#pragma unroll
                    for (int j = 0; j < 4; ++j)
                        acc[i][j] = __builtin_amdgcn_mfma_f32_16x16x32_bf16(bfr[j], af[i], acc[i][j], 0, 0, 0);
            } else {
#pragma unroll
                for (int i = 0; i < MI; ++i)
#pragma unroll
                    for (int j = 0; j < 4; ++j)
                        acc[i][j] = __builtin_amdgcn_mfma_f32_16x16x32_bf16(af[i], bfr[j], acc[i][j], 0, 0, 0);
            }
        }
        __builtin_amdgcn_s_setprio(0);
    };

    stage(0, As, Bs);
    stage(64, As + ASZ, Bs + BSZ);
    waitvm<SL>();
    bar();
#pragma unroll
    for (int s = 0; s < NSTEP; ++s) {
        const int cur = s & 1;
        compute(As + cur * ASZ, Bs + cur * BSZ);
        if (s == NSTEP - 1) break;
        bar();
        if (s + 2 < NSTEP) {
            stage((s + 2) * 64, As + cur * ASZ, Bs + cur * BSZ);
            waitvm<SL>();
        } else {
            waitvm<0>();
        }
        bar();
    }
    if (mode == 1) {
#pragma unroll
        for (int j = 0; j < 4; ++j) {
#pragma unroll
            for (int r = 0; r < 4; ++r) {
                int d = n0 + wn + j * 16 + quad * 4 + r;
                float bv = bias[d];
                int h = d >> 6, dk = d & 63;
#pragma unroll
                for (int i = 0; i < MI; ++i) {
                    int token = m0 + wm + i * 16 + lm;
                    int s = token >> 1, b = token & 1;
                    ((bf16*)out)[((size_t)(b * NH + h) * DKH + dk) * S_LEN + s] =
                        (bf16)(acc[i][j][r] + bv);
                }
            }
        }
        return;
    }
#pragma unroll
    for (int j = 0; j < 4; ++j) {
        float bcol = bias[n0 + wn + j * 16 + lm];
#pragma unroll
        for (int i = 0; i < MI; ++i)
#pragma unroll
            for (int r = 0; r < 4; ++r) acc[i][j][r] += bcol;
    }
#pragma unroll
    for (int i = 0; i < MI; ++i) {
#pragma unroll
        for (int j = 0; j < 4; ++j) {
            int col = n0 + wn + j * 16 + lm;
#pragma unroll
            for (int r = 0; r < 4; ++r) {
                int row = m0 + wm + i * 16 + quad * 4 + r;
                float val = acc[i][j][r];
                if (mode == 2) {
                    ((float*)out)[(size_t)row * DM + col] = val;
                } else {
                    int s = row >> 1, dk = col & 63;
                    float c = cosp[s * 64 + dk], sn = sinp[s * 64 + dk];
                    float partner = acc[i][j ^ 2][r];
                    float v2 = val * c + (dk < 32 ? -partner : partner) * sn;
                    if (mode == 3) v2 *= 0.125f * 1.44269504088896f;
                    ((bf16*)out)[(size_t)row * DM + col] = (bf16)v2;
                }
            }
        }
    }
}

struct QKVArgs {
    const bf16* A[3]; const bf16* W[3]; const float* bias[3];
    void* out[3]; const float* cs[3]; const float* sn[3]; int mode[3];
};

// (256,2): VGPR cap 256. R2: XCD-contiguous bijective tile swizzle (kept).
__global__ __launch_bounds__(256, 2) void gemm_qkv(QKVArgs args) {
    __shared__ __align__(16) bf16 As[2 * 8192];  // dbuf x [128][64]
    __shared__ __align__(16) bf16 Bs[2 * 8192];
    int z = blockIdx.z;
    int bid = blockIdx.y * 8 + blockIdx.x;       // 0..255 per z
    int swz = (bid & 7) * 32 + (bid >> 3);
    int bx = swz & 7, by = swz >> 3;
    gemm_core<4>(args.A[z], args.W[z], args.bias[z], args.out[z], args.mode[z],
                 args.cs[z], args.sn[z], As, Bs, bx, by);
}

// R13: (256,3) — VGPR cap ~170 (core uses 88 measured R9, no spill risk);
// LDS 48KB x 3 = 144 <= 160 -> 3 blocks/CU, grid 512 fully resident w/ slack.
__global__ __launch_bounds__(256, 3) void gemm_one(const bf16* __restrict__ A, const bf16* __restrict__ Bt,
                                                   const float* __restrict__ bias, void* __restrict__ out) {
    __shared__ __align__(16) bf16 As[2 * 8192];
    __shared__ __align__(16) bf16 Bs[2 * 4096];
    int bid = blockIdx.y * 16 + blockIdx.x;
    int swz = (bid & 7) * 64 + (bid >> 3);
    int bx = swz & 15, by = swz >> 4;
    gemm_core<2>(A, Bt, bias, out, 2, nullptr, nullptr, As, Bs, bx, by);
}

// ---------------- Flash attention v6 + R13 occupancy bump ----------------
// R13: __launch_bounds__(256,3) — LDS 41.5KB x 3 = 124.5 <= 160, blocks are
// independent (no inter-block convoy; R6's hazard doesn't apply). If the
// VGPR cap (~170) forces spill, wall regresses -> revert next round.
__global__ __launch_bounds__(256, 3) void flash_kernel(const bf16* __restrict__ qp, const bf16* __restrict__ kp,
                                                       const bf16* __restrict__ vT, bf16* __restrict__ ctx) {
    int qta = blockIdx.x;        // 0..15
    int qtb = 31 - qta;          // 16..31
    int bh = blockIdx.y;
    int b = bh >> 4, h = bh & 15;
    int t = threadIdx.x, lane = t & 63, wave = t >> 6;
    int lm = lane & 15, quad = lane >> 4;
    __shared__ __align__(16) bf16 Ks[2][64 * 64];
    __shared__ __align__(16) bf16 Vs[2][64 * 64];
    __shared__ __align__(16) uint32_t Pb[4][16 * 37];
    uint32_t* pw = &Pb[wave][0];
    const int q0[2] = {qta * 64 + wave * 16, qtb * 64 + wave * 16};

    bf16x8 aq[2][2];
#pragma unroll
    for (int u = 0; u < 2; ++u) {
        const bf16* qrow = qp + ((size_t)(q0[u] + lm) * BATCH + b) * DM + h * DKH;
        aq[u][0] = *(const bf16x8*)(qrow + quad * 8);
        aq[u][1] = *(const bf16x8*)(qrow + 32 + quad * 8);
    }
    f32x4 o[2][4] = {};
    float l_acc[2] = {0.f, 0.f};

    int r0 = t >> 3, c0 = t & 7;
    int r1 = r0 + 32;
    const bf16* kg0 = kp + ((size_t)r0 * BATCH + b) * DM + h * DKH + c0 * 8;
    const bf16* kg1 = kp + ((size_t)r1 * BATCH + b) * DM + h * DKH + c0 * 8;
    const bf16* vg0 = vT + ((size_t)(bh * DKH + r0)) * S_LEN + c0 * 8;
    const bf16* vg1 = vT + ((size_t)(bh * DKH + r1)) * S_LEN + c0 * 8;
    int lk0 = r0 * 64 + (c0 ^ (r0 & 7)) * 8;
    int lk1 = r1 * 64 + (c0 ^ (r1 & 7)) * 8;
    const size_t kstep = (size_t)64 * BATCH * DM;

    const int niter = qtb + 1;
    bf16x8 ka = *(const bf16x8*)kg0;
    bf16x8 kb2 = *(const bf16x8*)kg1;
    bf16x8 va = *(const bf16x8*)vg0;
    bf16x8 vb2 = *(const bf16x8*)vg1;
    *(bf16x8*)(Ks[0] + lk0) = ka;
    *(bf16x8*)(Ks[0] + lk1) = kb2;
    *(bf16x8*)(Vs[0] + lk0) = va;
    *(bf16x8*)(Vs[0] + lk1) = vb2;
    __syncthreads();

    for (int it = 0; it < niter; ++it) {
        const int cur = it & 1;
        int kv0 = it << 6;
        bool hn = (it + 1) < niter;
        if (hn) {
            size_t koff = (size_t)(it + 1) * kstep;
            ka  = *(const bf16x8*)(kg0 + koff);
            kb2 = *(const bf16x8*)(kg1 + koff);
            va  = *(const bf16x8*)(vg0 + (it + 1) * 64);
            vb2 = *(const bf16x8*)(vg1 + (it + 1) * 64);
        }
        bf16x8 kf[4][2];
#pragma unroll
        for (int nt = 0; nt < 4; ++nt) {
            int krow = nt * 16 + lm;
            kf[nt][0] = *(const bf16x8*)(Ks[cur] + krow * 64 + ((quad ^ (krow & 7)) * 8));
            kf[nt][1] = *(const bf16x8*)(Ks[cur] + krow * 64 + (((quad + 4) ^ (krow & 7)) * 8));
        }
#pragma unroll
        for (int u = 0; u < 2; ++u) {
            if (u == 0 && kv0 > q0[0] + 15) continue;
            const f32x4 zero = {0.f, 0.f, 0.f, 0.f};
            f32x4 sc[4];
            __builtin_amdgcn_s_setprio(1);
#pragma unroll
            for (int nt = 0; nt < 4; ++nt) {
                sc[nt] = __builtin_amdgcn_mfma_f32_16x16x32_bf16(kf[nt][0], aq[u][0], zero, 0, 0, 0);
                sc[nt] = __builtin_amdgcn_mfma_f32_16x16x32_bf16(kf[nt][1], aq[u][1], sc[nt], 0, 0, 0);
            }
            __builtin_amdgcn_s_setprio(0);
            if (kv0 + 63 > q0[u]) {
#pragma unroll
                for (int nt = 0; nt < 4; ++nt)
#pragma unroll
                    for (int r = 0; r < 4; ++r) {
                        int kvg = kv0 + nt * 16 + quad * 4 + r;
                        if (kvg > q0[u] + lm) sc[nt][r] = -1e30f;
                    }
            }
            float rs = 0.f;
            uint32_t pk[8];
#pragma unroll
            for (int nt = 0; nt < 4; ++nt)
#pragma unroll
                for (int rp = 0; rp < 2; ++rp) {
                    float p0 = exp2f(sc[nt][2 * rp]);
                    float p1 = exp2f(sc[nt][2 * rp + 1]);
                    rs += p0 + p1;
                    pk[nt * 2 + rp] = pack2(p0, p1);
                }
            l_acc[u] += rs;
#pragma unroll
            for (int nt = 0; nt < 4; ++nt)
#pragma unroll
                for (int rp = 0; rp < 2; ++rp)
                    pw[lm * 37 + nt * 8 + quad * 2 + rp] = pk[nt * 2 + rp];
            __builtin_amdgcn_wave_barrier();
            const uint32_t* pr = pw + lm * 37;
            bf16x8 pf0 = *(const bf16x8*)(pr + quad * 4);
            bf16x8 pf1 = *(const bf16x8*)(pr + 16 + quad * 4);
            __builtin_amdgcn_s_setprio(1);
#pragma unroll
            for (int dt = 0; dt < 4; ++dt) {
                int vrow = dt * 16 + lm;
                bf16x8 vf0 = *(const bf16x8*)(Vs[cur] + vrow * 64 + ((quad ^ (vrow & 7)) * 8));
                bf16x8 vf1 = *(const bf16x8*)(Vs[cur] + vrow * 64 + (((quad + 4) ^ (vrow & 7)) * 8));
                o[u][dt] = __builtin_amdgcn_mfma_f32_16x16x32_bf16(vf0, pf0, o[u][dt], 0, 0, 0);
                o[u][dt] = __builtin_amdgcn_mfma_f32_16x16x32_bf16(vf1, pf1, o[u][dt], 0, 0, 0);
            }
            __builtin_amdgcn_s_setprio(0);
            __builtin_amdgcn_wave_barrier();
        }
        if (hn) {
            *(bf16x8*)(Ks[cur ^ 1] + lk0) = ka;
            *(bf16x8*)(Ks[cur ^ 1] + lk1) = kb2;
            *(bf16x8*)(Vs[cur ^ 1] + lk0) = va;
            *(bf16x8*)(Vs[cur ^ 1] + lk1) = vb2;
        }
        __syncthreads();
    }
#pragma unroll
    for (int u = 0; u < 2; ++u) {
        float l = l_acc[u];
        l += __shfl_xor(l, 16, 64);
        l += __shfl_xor(l, 32, 64);
        float linv = 1.f / l;
        int qg = q0[u] + lm;
        bf16* crow = ctx + ((size_t)qg * BATCH + b) * DM + h * DKH;
#pragma unroll
        for (int dt = 0; dt < 4; ++dt) {
            bf16x4 v;
#pragma unroll
            for (int r = 0; r < 4; ++r) v[r] = (bf16)(o[u][dt][r] * linv);
            *(bf16x4*)(crow + dt * 16 + quad * 4) = v;
        }
    }
}

extern "C" void kernel_launch(void* const* d_in, const int* in_sizes, int n_in,
                              void* d_out, int out_size, void* d_ws, size_t ws_size,
                              hipStream_t stream) {
    const float* Q    = (const float*)d_in[0];
    const float* K    = (const float*)d_in[1];
    const float* V    = (const float*)d_in[2];
    const float* Wq   = (const float*)d_in[3];
    const float* bq   = (const float*)d_in[4];
    const float* Wk   = (const float*)d_in[5];
    const float* bk   = (const float*)d_in[6];
    const float* Wv   = (const float*)d_in[7];
    const float* bv   = (const float*)d_in[8];
    const float* Wo   = (const float*)d_in[9];
    const float* bo   = (const float*)d_in[10];
    const float* qcos = (const float*)d_in[11];
    const float* qsin = (const float*)d_in[12];
    const float* kcos = (const float*)d_in[13];
    const float* ksin = (const float*)d_in[14];
    // d_in[15] = mask: deterministic causal triu(k=1); applied analytically.

    char* ws = (char*)d_ws;
    const size_t SZ_ACT = (size_t)MTOT * DM * sizeof(bf16);  // 8 MiB
    const size_t SZ_W   = (size_t)DM * DM * sizeof(bf16);    // 2 MiB
    bf16* qb  = (bf16*)ws; ws += SZ_ACT;
    bf16* kb  = (bf16*)ws; ws += SZ_ACT;
    bf16* vb  = (bf16*)ws; ws += SZ_ACT;
    bf16* wqb = (bf16*)ws; ws += SZ_W;
    bf16* wkb = (bf16*)ws; ws += SZ_W;
    bf16* wvb = (bf16*)ws; ws += SZ_W;
    bf16* wob = (bf16*)ws; ws += SZ_W;
    bf16* qpr = (bf16*)ws; ws += SZ_ACT;
    bf16* kpr = (bf16*)ws; ws += SZ_ACT;
    bf16* vTp = (bf16*)ws; ws += SZ_ACT;
    bf16* ctx = (bf16*)ws; ws += SZ_ACT;

    ConvArgs ca;
    ca.src[0] = Q;  ca.dst[0] = qb;
    ca.src[1] = K;  ca.dst[1] = kb;
    ca.src[2] = V;  ca.dst[2] = vb;
    ca.src[3] = Wq; ca.dst[3] = wqb;
    ca.src[4] = Wk; ca.dst[4] = wkb;
    ca.src[5] = Wv; ca.dst[5] = wvb;
    ca.src[6] = Wo; ca.dst[6] = wob;
    convert_all<<<8192, 256, 0, stream>>>(ca);

    QKVArgs qa;
    qa.A[0] = qb; qa.W[0] = wqb; qa.bias[0] = bq; qa.out[0] = qpr; qa.mode[0] = 3; qa.cs[0] = qcos; qa.sn[0] = qsin;
    qa.A[1] = kb; qa.W[1] = wkb; qa.bias[1] = bk; qa.out[1] = kpr; qa.mode[1] = 4; qa.cs[1] = kcos; qa.sn[1] = ksin;
    qa.A[2] = vb; qa.W[2] = wvb; qa.bias[2] = bv; qa.out[2] = vTp; qa.mode[2] = 1; qa.cs[2] = nullptr; qa.sn[2] = nullptr;
    gemm_qkv<<<dim3(DM / 128, MTOT / 128, 3), 256, 0, stream>>>(qa);

    flash_kernel<<<dim3(16, BATCH * NH), 256, 0, stream>>>(qpr, kpr, vTp, ctx);

    gemm_one<<<dim3(DM / 64, MTOT / 128), 256, 0, stream>>>(ctx, wob, bo, (float*)d_out);
}

// Round 14
// 261.721 us; speedup vs baseline: 1.0131x; 1.0088x over previous
//
#include <hip/hip_runtime.h>
#include <cstdint>
#include <cstddef>

typedef __bf16 bf16;
typedef __bf16 bf16x2 __attribute__((ext_vector_type(2)));
typedef __bf16 bf16x4 __attribute__((ext_vector_type(4)));
typedef __bf16 bf16x8 __attribute__((ext_vector_type(8)));
typedef float f32x4 __attribute__((ext_vector_type(4)));

#define S_LEN 2048
#define BATCH 2
#define DM 1024
#define NH 16
#define DKH 64
#define MTOT (S_LEN * BATCH)  // 4096

// async global->LDS, 16B per lane; LDS dest = wave-uniform base + lane*16
__device__ __forceinline__ void gload_lds16(const void* g, void* l) {
    __builtin_amdgcn_global_load_lds((const __attribute__((address_space(1))) uint32_t*)g,
                                     (__attribute__((address_space(3))) uint32_t*)l, 16, 0, 0);
}

__device__ __forceinline__ uint32_t pack2(float a, float b) {
    bf16x2 v; v[0] = (bf16)a; v[1] = (bf16)b;
    return __builtin_bit_cast(uint32_t, v);
}

// raw barrier + counted vmcnt (T4): __syncthreads would drain vmcnt(0)
__device__ __forceinline__ void bar() { asm volatile("s_barrier" ::: "memory"); }
template<int N>
__device__ __forceinline__ void waitvm() {
    asm volatile("s_waitcnt vmcnt(%0)" :: "n"(N) : "memory");
}

// ---------------- fused fp32 -> bf16 convert ----------------
struct ConvArgs { const float* src[7]; bf16* dst[7]; };

__global__ __launch_bounds__(256) void convert_all(ConvArgs a) {
    int gid = blockIdx.x * 256 + threadIdx.x;
    int tid, off;
    if (gid < 3 * 524288) { tid = gid >> 19; off = gid & 524287; }
    else { int r = gid - 3 * 524288; tid = 3 + (r >> 17); off = r & 131071; }
    const float4* s4 = (const float4*)a.src[tid];
    float4 x = s4[2 * off], y = s4[2 * off + 1];
    bf16x8 v;
    v[0] = (bf16)x.x; v[1] = (bf16)x.y; v[2] = (bf16)x.z; v[3] = (bf16)x.w;
    v[4] = (bf16)y.x; v[5] = (bf16)y.y; v[6] = (bf16)y.z; v[7] = (bf16)y.w;
    *(bf16x8*)(a.dst[tid] + 8 * (size_t)off) = v;
}

// ---------------- GEMM core: C = A(M,K) @ Bt(N,K)^T + bias ----------------
// R9 core (best verified: qkv 59-60us). Full-line staging granule, row-major
// [128][64] LDS with G4 XOR swizzle (rule-#21 involution, conflicts=0), T4
// depth-2 counted-vmcnt pipeline, T5 setprio, (256,2)/(256,3).
// STRUCTURE LEDGER (do not revisit): R6 BK=32 (72us); R7 direct-to-reg (141us
// scratch spill); R12 256^2 8-phase port (65.7us — VGPR cap pinch + 25% CUs
// idle; m248 geometry doesn't transfer here).
template<int MI>
__device__ __forceinline__ void gemm_core(const bf16* __restrict__ A, const bf16* __restrict__ Bt,
                                          const float* __restrict__ bias, void* __restrict__ out,
                                          int mode, const float* __restrict__ cosp,
                                          const float* __restrict__ sinp, bf16* As, bf16* Bs,
                                          int bx, int by) {
    constexpr int TN = (MI == 4) ? 128 : 64;
    constexpr int ASZ = 8192;
    constexpr int BSZ = (TN == 128) ? 8192 : 4096;
    constexpr int SL  = (MI == 4) ? 8 : 6;
    constexpr int NSTEP = DM / 64;
    int t = threadIdx.x;
    int lane = t & 63, wave = t >> 6;
    int lm = lane & 15, quad = lane >> 4;
    int m0 = by * 128, n0 = bx * TN;
    int wm, wn;
    if constexpr (MI == 4) { wm = (wave >> 1) * 64; wn = (wave & 1) * 64; }
    else { wm = wave * 32; wn = 0; }
    f32x4 acc[MI][4] = {};

    int rw = lane >> 3;
    int csw = ((lane & 7) ^ rw) * 8;
    const bf16* agp = A + (size_t)(m0 + wave * 32 + rw) * DM + csw;
    const bf16* bgp;
    if constexpr (MI == 4) bgp = Bt + (size_t)(n0 + wave * 32 + rw) * DM + csw;
    else                   bgp = Bt + (size_t)(n0 + wave * 16 + rw) * DM + csw;

    auto stage = [&](int k0, bf16* Ab, bf16* Bb) {
#pragma unroll
        for (int q = 0; q < 4; ++q)
            gload_lds16(agp + (size_t)q * 8 * DM + k0, Ab + wave * 2048 + q * 512);
        if constexpr (MI == 4) {
#pragma unroll
            for (int q = 0; q < 4; ++q)
                gload_lds16(bgp + (size_t)q * 8 * DM + k0, Bb + wave * 2048 + q * 512);
        } else {
#pragma unroll
            for (int q = 0; q < 2; ++q)
                gload_lds16(bgp + (size_t)q * 8 * DM + k0, Bb + wave * 1024 + q * 512);
        }
    };
    const int rsw = lm & 7;
    auto compute = [&](const bf16* Ar, const bf16* Br) {
        __builtin_amdgcn_s_setprio(1);
#pragma unroll
        for (int h = 0; h < 2; ++h) {
            const int slot = ((h * 4 + quad) ^ rsw) * 8;
            bf16x8 af[MI], bfr[4];
#pragma unroll
            for (int i = 0; i < MI; ++i)
                af[i] = *(const bf16x8*)(Ar + (wm + i * 16 + lm) * 64 + slot);
#pragma unroll
            for (int j = 0; j < 4; ++j)
                bfr[j] = *(const bf16x8*)(Br + (wn + j * 16 + lm) * 64 + slot);
            if (mode == 1) {
#pragma unroll
                for (int i = 0; i < MI; ++i)
#pragma unroll
                    for (int j = 0; j < 4; ++j)
                        acc[i][j] = __builtin_amdgcn_mfma_f32_16x16x32_bf16(bfr[j], af[i], acc[i][j], 0, 0, 0);
            } else {
#pragma unroll
                for (int i = 0; i < MI; ++i)
#pragma unroll
                    for (int j = 0; j < 4; ++j)
                        acc[i][j] = __builtin_amdgcn_mfma_f32_16x16x32_bf16(af[i], bfr[j], acc[i][j], 0, 0, 0);
            }
        }
        __builtin_amdgcn_s_setprio(0);
    };

    stage(0, As, Bs);
    stage(64, As + ASZ, Bs + BSZ);
    waitvm<SL>();
    bar();
#pragma unroll
    for (int s = 0; s < NSTEP; ++s) {
        const int cur = s & 1;
        compute(As + cur * ASZ, Bs + cur * BSZ);
        if (s == NSTEP - 1) break;
        bar();
        if (s + 2 < NSTEP) {
            stage((s + 2) * 64, As + cur * ASZ, Bs + cur * BSZ);
            waitvm<SL>();
        } else {
            waitvm<0>();
        }
        bar();
    }
    if (mode == 1) {
#pragma unroll
        for (int j = 0; j < 4; ++j) {
#pragma unroll
            for (int r = 0; r < 4; ++r) {
                int d = n0 + wn + j * 16 + quad * 4 + r;
                float bv = bias[d];
                int h = d >> 6, dk = d & 63;
#pragma unroll
                for (int i = 0; i < MI; ++i) {
                    int token = m0 + wm + i * 16 + lm;
                    int s = token >> 1, b = token & 1;
                    ((bf16*)out)[((size_t)(b * NH + h) * DKH + dk) * S_LEN + s] =
                        (bf16)(acc[i][j][r] + bv);
                }
            }
        }
        return;
    }
#pragma unroll
    for (int j = 0; j < 4; ++j) {
        float bcol = bias[n0 + wn + j * 16 + lm];
#pragma unroll
        for (int i = 0; i < MI; ++i)
#pragma unroll
            for (int r = 0; r < 4; ++r) acc[i][j][r] += bcol;
    }
#pragma unroll
    for (int i = 0; i < MI; ++i) {
#pragma unroll
        for (int j = 0; j < 4; ++j) {
            int col = n0 + wn + j * 16 + lm;
#pragma unroll
            for (int r = 0; r < 4; ++r) {
                int row = m0 + wm + i * 16 + quad * 4 + r;
                float val = acc[i][j][r];
                if (mode == 2) {
                    ((float*)out)[(size_t)row * DM + col] = val;
                } else {
                    int s = row >> 1, dk = col & 63;
                    float c = cosp[s * 64 + dk], sn = sinp[s * 64 + dk];
                    float partner = acc[i][j ^ 2][r];
                    float v2 = val * c + (dk < 32 ? -partner : partner) * sn;
                    if (mode == 3) v2 *= 0.125f * 1.44269504088896f;
                    ((bf16*)out)[(size_t)row * DM + col] = (bf16)v2;
                }
            }
        }
    }
}

struct QKVArgs {
    const bf16* A[3]; const bf16* W[3]; const float* bias[3];
    void* out[3]; const float* cs[3]; const float* sn[3]; int mode[3];
};

// (256,2): VGPR cap 256. R2: XCD-contiguous bijective tile swizzle (kept).
__global__ __launch_bounds__(256, 2) void gemm_qkv(QKVArgs args) {
    __shared__ __align__(16) bf16 As[2 * 8192];  // dbuf x [128][64]
    __shared__ __align__(16) bf16 Bs[2 * 8192];
    int z = blockIdx.z;
    int bid = blockIdx.y * 8 + blockIdx.x;       // 0..255 per z
    int swz = (bid & 7) * 32 + (bid >> 3);
    int bx = swz & 7, by = swz >> 3;
    gemm_core<4>(args.A[z], args.W[z], args.bias[z], args.out[z], args.mode[z],
                 args.cs[z], args.sn[z], As, Bs, bx, by);
}

__global__ __launch_bounds__(256, 3) void gemm_one(const bf16* __restrict__ A, const bf16* __restrict__ Bt,
                                                   const float* __restrict__ bias, void* __restrict__ out) {
    __shared__ __align__(16) bf16 As[2 * 8192];
    __shared__ __align__(16) bf16 Bs[2 * 4096];
    int bid = blockIdx.y * 16 + blockIdx.x;
    int swz = (bid & 7) * 64 + (bid >> 3);
    int bx = swz & 15, by = swz >> 4;
    gemm_core<2>(A, Bt, bias, out, 2, nullptr, nullptr, As, Bs, bx, by);
}

// ---------------- Flash attention v7: per-CU loop-length balancing ----------------
// R14: R13 counters showed niter = 32-qta varies 17..32 while dispatch geometry
// (id = x+16y, 512 blocks, 2/CU) pairs id with id+256 -> SAME x -> same qta ->
// same niter on one CU: per-CU work spread 34..64 iters. Remap
// qta = (y<16) ? x : 15-x  => id and id+256 have COMPLEMENTARY niter
// (sum = 49 const) -> per-CU summed loop length equal. (qta,bh) coverage still
// exactly once; math/addressing unchanged.
__global__ __launch_bounds__(256, 3) void flash_kernel(const bf16* __restrict__ qp, const bf16* __restrict__ kp,
                                                       const bf16* __restrict__ vT, bf16* __restrict__ ctx) {
    int qta = (blockIdx.y < 16) ? blockIdx.x : 15 - blockIdx.x;   // R14 balance map
    int qtb = 31 - qta;          // 16..31
    int bh = blockIdx.y;
    int b = bh >> 4, h = bh & 15;
    int t = threadIdx.x, lane = t & 63, wave = t >> 6;
    int lm = lane & 15, quad = lane >> 4;
    __shared__ __align__(16) bf16 Ks[2][64 * 64];
    __shared__ __align__(16) bf16 Vs[2][64 * 64];
    __shared__ __align__(16) uint32_t Pb[4][16 * 37];
    uint32_t* pw = &Pb[wave][0];
    const int q0[2] = {qta * 64 + wave * 16, qtb * 64 + wave * 16};

    bf16x8 aq[2][2];
#pragma unroll
    for (int u = 0; u < 2; ++u) {
        const bf16* qrow = qp + ((size_t)(q0[u] + lm) * BATCH + b) * DM + h * DKH;
        aq[u][0] = *(const bf16x8*)(qrow + quad * 8);
        aq[u][1] = *(const bf16x8*)(qrow + 32 + quad * 8);
    }
    f32x4 o[2][4] = {};
    float l_acc[2] = {0.f, 0.f};

    int r0 = t >> 3, c0 = t & 7;
    int r1 = r0 + 32;
    const bf16* kg0 = kp + ((size_t)r0 * BATCH + b) * DM + h * DKH + c0 * 8;
    const bf16* kg1 = kp + ((size_t)r1 * BATCH + b) * DM + h * DKH + c0 * 8;
    const bf16* vg0 = vT + ((size_t)(bh * DKH + r0)) * S_LEN + c0 * 8;
    const bf16* vg1 = vT + ((size_t)(bh * DKH + r1)) * S_LEN + c0 * 8;
    int lk0 = r0 * 64 + (c0 ^ (r0 & 7)) * 8;
    int lk1 = r1 * 64 + (c0 ^ (r1 & 7)) * 8;
    const size_t kstep = (size_t)64 * BATCH * DM;

    const int niter = qtb + 1;
    bf16x8 ka = *(const bf16x8*)kg0;
    bf16x8 kb2 = *(const bf16x8*)kg1;
    bf16x8 va = *(const bf16x8*)vg0;
    bf16x8 vb2 = *(const bf16x8*)vg1;
    *(bf16x8*)(Ks[0] + lk0) = ka;
    *(bf16x8*)(Ks[0] + lk1) = kb2;
    *(bf16x8*)(Vs[0] + lk0) = va;
    *(bf16x8*)(Vs[0] + lk1) = vb2;
    __syncthreads();

    for (int it = 0; it < niter; ++it) {
        const int cur = it & 1;
        int kv0 = it << 6;
        bool hn = (it + 1) < niter;
        if (hn) {
            size_t koff = (size_t)(it + 1) * kstep;
            ka  = *(const bf16x8*)(kg0 + koff);
            kb2 = *(const bf16x8*)(kg1 + koff);
            va  = *(const bf16x8*)(vg0 + (it + 1) * 64);
            vb2 = *(const bf16x8*)(vg1 + (it + 1) * 64);
        }
        bf16x8 kf[4][2];
#pragma unroll
        for (int nt = 0; nt < 4; ++nt) {
            int krow = nt * 16 + lm;
            kf[nt][0] = *(const bf16x8*)(Ks[cur] + krow * 64 + ((quad ^ (krow & 7)) * 8));
            kf[nt][1] = *(const bf16x8*)(Ks[cur] + krow * 64 + (((quad + 4) ^ (krow & 7)) * 8));
        }
#pragma unroll
        for (int u = 0; u < 2; ++u) {
            if (u == 0 && kv0 > q0[0] + 15) continue;
            const f32x4 zero = {0.f, 0.f, 0.f, 0.f};
            f32x4 sc[4];
            __builtin_amdgcn_s_setprio(1);
#pragma unroll
            for (int nt = 0; nt < 4; ++nt) {
                sc[nt] = __builtin_amdgcn_mfma_f32_16x16x32_bf16(kf[nt][0], aq[u][0], zero, 0, 0, 0);
                sc[nt] = __builtin_amdgcn_mfma_f32_16x16x32_bf16(kf[nt][1], aq[u][1], sc[nt], 0, 0, 0);
            }
            __builtin_amdgcn_s_setprio(0);
            if (kv0 + 63 > q0[u]) {
#pragma unroll
                for (int nt = 0; nt < 4; ++nt)
#pragma unroll
                    for (int r = 0; r < 4; ++r) {
                        int kvg = kv0 + nt * 16 + quad * 4 + r;
                        if (kvg > q0[u] + lm) sc[nt][r] = -1e30f;
                    }
            }
            float rs = 0.f;
            uint32_t pk[8];
#pragma unroll
            for (int nt = 0; nt < 4; ++nt)
#pragma unroll
                for (int rp = 0; rp < 2; ++rp) {
                    float p0 = exp2f(sc[nt][2 * rp]);
                    float p1 = exp2f(sc[nt][2 * rp + 1]);
                    rs += p0 + p1;
                    pk[nt * 2 + rp] = pack2(p0, p1);
                }
            l_acc[u] += rs;
#pragma unroll
            for (int nt = 0; nt < 4; ++nt)
#pragma unroll
                for (int rp = 0; rp < 2; ++rp)
                    pw[lm * 37 + nt * 8 + quad * 2 + rp] = pk[nt * 2 + rp];
            __builtin_amdgcn_wave_barrier();
            const uint32_t* pr = pw + lm * 37;
            bf16x8 pf0 = *(const bf16x8*)(pr + quad * 4);
            bf16x8 pf1 = *(const bf16x8*)(pr + 16 + quad * 4);
            __builtin_amdgcn_s_setprio(1);
#pragma unroll
            for (int dt = 0; dt < 4; ++dt) {
                int vrow = dt * 16 + lm;
                bf16x8 vf0 = *(const bf16x8*)(Vs[cur] + vrow * 64 + ((quad ^ (vrow & 7)) * 8));
                bf16x8 vf1 = *(const bf16x8*)(Vs[cur] + vrow * 64 + (((quad + 4) ^ (vrow & 7)) * 8));
                o[u][dt] = __builtin_amdgcn_mfma_f32_16x16x32_bf16(vf0, pf0, o[u][dt], 0, 0, 0);
                o[u][dt] = __builtin_amdgcn_mfma_f32_16x16x32_bf16(vf1, pf1, o[u][dt], 0, 0, 0);
            }
            __builtin_amdgcn_s_setprio(0);
            __builtin_amdgcn_wave_barrier();
        }
        if (hn) {
            *(bf16x8*)(Ks[cur ^ 1] + lk0) = ka;
            *(bf16x8*)(Ks[cur ^ 1] + lk1) = kb2;
            *(bf16x8*)(Vs[cur ^ 1] + lk0) = va;
            *(bf16x8*)(Vs[cur ^ 1] + lk1) = vb2;
        }
        __syncthreads();
    }
#pragma unroll
    for (int u = 0; u < 2; ++u) {
        float l = l_acc[u];
        l += __shfl_xor(l, 16, 64);
        l += __shfl_xor(l, 32, 64);
        float linv = 1.f / l;
        int qg = q0[u] + lm;
        bf16* crow = ctx + ((size_t)qg * BATCH + b) * DM + h * DKH;
#pragma unroll
        for (int dt = 0; dt < 4; ++dt) {
            bf16x4 v;
#pragma unroll
            for (int r = 0; r < 4; ++r) v[r] = (bf16)(o[u][dt][r] * linv);
            *(bf16x4*)(crow + dt * 16 + quad * 4) = v;
        }
    }
}

extern "C" void kernel_launch(void* const* d_in, const int* in_sizes, int n_in,
                              void* d_out, int out_size, void* d_ws, size_t ws_size,
                              hipStream_t stream) {
    const float* Q    = (const float*)d_in[0];
    const float* K    = (const float*)d_in[1];
    const float* V    = (const float*)d_in[2];
    const float* Wq   = (const float*)d_in[3];
    const float* bq   = (const float*)d_in[4];
    const float* Wk   = (const float*)d_in[5];
    const float* bk   = (const float*)d_in[6];
    const float* Wv   = (const float*)d_in[7];
    const float* bv   = (const float*)d_in[8];
    const float* Wo   = (const float*)d_in[9];
    const float* bo   = (const float*)d_in[10];
    const float* qcos = (const float*)d_in[11];
    const float* qsin = (const float*)d_in[12];
    const float* kcos = (const float*)d_in[13];
    const float* ksin = (const float*)d_in[14];
    // d_in[15] = mask: deterministic causal triu(k=1); applied analytically.

    char* ws = (char*)d_ws;
    const size_t SZ_ACT = (size_t)MTOT * DM * sizeof(bf16);  // 8 MiB
    const size_t SZ_W   = (size_t)DM * DM * sizeof(bf16);    // 2 MiB
    bf16* qb  = (bf16*)ws; ws += SZ_ACT;
    bf16* kb  = (bf16*)ws; ws += SZ_ACT;
    bf16* vb  = (bf16*)ws; ws += SZ_ACT;
    bf16* wqb = (bf16*)ws; ws += SZ_W;
    bf16* wkb = (bf16*)ws; ws += SZ_W;
    bf16* wvb = (bf16*)ws; ws += SZ_W;
    bf16* wob = (bf16*)ws; ws += SZ_W;
    bf16* qpr = (bf16*)ws; ws += SZ_ACT;
    bf16* kpr = (bf16*)ws; ws += SZ_ACT;
    bf16* vTp = (bf16*)ws; ws += SZ_ACT;
    bf16* ctx = (bf16*)ws; ws += SZ_ACT;

    ConvArgs ca;
    ca.src[0] = Q;  ca.dst[0] = qb;
    ca.src[1] = K;  ca.dst[1] = kb;
    ca.src[2] = V;  ca.dst[2] = vb;
    ca.src[3] = Wq; ca.dst[3] = wqb;
    ca.src[4] = Wk; ca.dst[4] = wkb;
    ca.src[5] = Wv; ca.dst[5] = wvb;
    ca.src[6] = Wo; ca.dst[6] = wob;
    convert_all<<<8192, 256, 0, stream>>>(ca);

    QKVArgs qa;
    qa.A[0] = qb; qa.W[0] = wqb; qa.bias[0] = bq; qa.out[0] = qpr; qa.mode[0] = 3; qa.cs[0] = qcos; qa.sn[0] = qsin;
    qa.A[1] = kb; qa.W[1] = wkb; qa.bias[1] = bk; qa.out[1] = kpr; qa.mode[1] = 4; qa.cs[1] = kcos; qa.sn[1] = ksin;
    qa.A[2] = vb; qa.W[2] = wvb; qa.bias[2] = bv; qa.out[2] = vTp; qa.mode[2] = 1; qa.cs[2] = nullptr; qa.sn[2] = nullptr;
    gemm_qkv<<<dim3(DM / 128, MTOT / 128, 3), 256, 0, stream>>>(qa);

    flash_kernel<<<dim3(16, BATCH * NH), 256, 0, stream>>>(qpr, kpr, vTp, ctx);

    gemm_one<<<dim3(DM / 64, MTOT / 128), 256, 0, stream>>>(ctx, wob, bo, (float*)d_out);
}